// Round 16
// baseline (116.110 us; speedup 1.0000x reference)
//
#include <hip/hip_runtime.h>
#include <hip/hip_bf16.h>
#include <cstddef>

// Problem constants (EmbeddingEngine_47029891891415)
#define S_ 4
#define N_ 65536
#define K_ 64
#define D_ 256
#define P_ 8192

typedef __bf16 bf16x8 __attribute__((ext_vector_type(8)));
typedef float  f32x4  __attribute__((ext_vector_type(4)));

// Pack W [S][K=64][D=256] fp32 -> bf16 MFMA fragments in ws.
// wpack[(((s*2 + t)*16 + c)*64 + lane)*8 + i] =
//     bf16(W[s][t*32 + 8*(lane>>4) + i][c*16 + (lane&15)])
__global__ __launch_bounds__(256) void pack_w_kernel(const float* __restrict__ W,
                                                     __bf16* __restrict__ wpack) {
    int tid  = blockIdx.x * 256 + threadIdx.x;   // 0..65535
    int i    =  tid        & 7;
    int lane = (tid >> 3)  & 63;
    int c    = (tid >> 9)  & 15;
    int t    = (tid >> 13) & 1;
    int s    =  tid >> 14;
    int k    = t * 32 + 8 * (lane >> 4) + i;
    int col  = c * 16 + (lane & 15);
    wpack[tid] = (__bf16)W[(s * K_ + k) * D_ + col];
}

// R10 with ONE lever: SINGLE-PHASE epilogue. Whole 16x256 tile staged in
// LDS at once ([16][264] floats/wave, 67.6 KB/block -> 2 blocks/CU), then
// 16 back-to-back full-row stores: each instr = 64 lanes x 16B = ONE
// CONTIGUOUS 1KB row (the fillBuffer pattern). Eliminates the 2nd
// pass-turnaround (vmcnt->ds_write->lgkmcnt->ds_read->store serial chain);
// R12 measured +18us going 2->4 passes, extrapolating 2->1 saves ~9us.
// Tests turnaround-vs-residency causality in the profitable direction
// (residency drops 16 -> 8 waves/CU).
// Bank math: write (264j+16c+4g: 8 lanes/bank-quad = b128 minimum);
// read (4*lane quads: 8 lanes/quad = minimum). Conflict-free.
// All else R10-identical: NT token loads, swapped-operand MFMA
// (C/D m89/m91: col(lane&15)=token, row(g*4+reg)=d_local), NT stores.
__global__ __launch_bounds__(256) void embed_kernel(
        const float* __restrict__ tokens,    // [S][N][K] f32
        const float* __restrict__ bvec,      // [S][D] f32
        const float* __restrict__ pe,        // [P][D] f32
        const int*   __restrict__ idxs,      // [S][N] i32
        const int*   __restrict__ idxs_pe,   // [S][N] i32
        const __bf16* __restrict__ wpack,    // packed W fragments (L2)
        float* __restrict__ out) {           // [S*N][D] f32
    const int blk   = blockIdx.x;            // 0..4095
    const int s     = blk >> 10;             // 1024 tiles per stream
    const int tile  = blk & 1023;
    const int wave  = threadIdx.x >> 6;
    const int lane  = threadIdx.x & 63;
    const int j     = lane & 15;             // token within wave tile
    const int g     = lane >> 4;
    const int rowbase = tile * 64 + wave * 16;
    const int trowi   = rowbase + j;         // token row within stream

    __shared__ float lds[4][16][264];        // per-wave [row][256+8 pad]
    float* const wl = &lds[wave][0][0];

    // ---- token fragments: tok[trowi][k], k = t*32 + 8g + e (streaming)
    const float* trow = tokens + ((size_t)s * N_ + trowi) * K_;
    f32x4 t0lo = __builtin_nontemporal_load((const f32x4*)(trow +      8 * g));
    f32x4 t0hi = __builtin_nontemporal_load((const f32x4*)(trow +      8 * g + 4));
    f32x4 t1lo = __builtin_nontemporal_load((const f32x4*)(trow + 32 + 8 * g));
    f32x4 t1hi = __builtin_nontemporal_load((const f32x4*)(trow + 32 + 8 * g + 4));
    bf16x8 a0, a1;
#pragma unroll
    for (int e = 0; e < 4; ++e) {
        a0[e]     = (__bf16)t0lo[e];
        a0[e + 4] = (__bf16)t0hi[e];
        a1[e]     = (__bf16)t1lo[e];
        a1[e + 4] = (__bf16)t1hi[e];
    }

    // ---- W fragments (L2-resident) + MFMA (swapped operands)
    const bf16x8* wp0 = (const bf16x8*)wpack + (size_t)((s * 2 + 0) * 16) * 64;
    const bf16x8* wp1 = (const bf16x8*)wpack + (size_t)((s * 2 + 1) * 16) * 64;

    f32x4 acc[16];
#pragma unroll
    for (int c = 0; c < 16; ++c) acc[c] = (f32x4){0.f, 0.f, 0.f, 0.f};
#pragma unroll
    for (int c = 0; c < 16; ++c) {
        bf16x8 w0 = wp0[c * 64 + lane];
        bf16x8 w1 = wp1[c * 64 + lane];
        acc[c] = __builtin_amdgcn_mfma_f32_16x16x32_bf16(w0, a0, acc[c], 0, 0, 0);
        acc[c] = __builtin_amdgcn_mfma_f32_16x16x32_bf16(w1, a1, acc[c], 0, 0, 0);
    }

    // ---- Epilogue phase 1: gather pe + bias, stage WHOLE tile into LDS
    const int ipe  = idxs_pe[s * N_ + trowi];
    const float* __restrict__ perow = pe + (size_t)ipe * D_ + g * 4;
    const float* __restrict__ brow  = bvec + s * D_ + g * 4;
#pragma unroll
    for (int c = 0; c < 16; ++c) {
        f32x4 pev = *(const f32x4*)(perow + c * 16);
        f32x4 bbv = *(const f32x4*)(brow  + c * 16);
        f32x4 o   = acc[c] + bbv + pev;
        *(f32x4*)(wl + j * 264 + c * 16 + g * 4) = o;
    }

    // ---- Epilogue phase 2: 16 back-to-back full-row 1KB NT store bursts
#pragma unroll
    for (int r = 0; r < 16; ++r) {
        const int orow_r = idxs[s * N_ + rowbase + r];   // wave-uniform
        f32x4 v = *(const f32x4*)(wl + r * 264 + lane * 4);
        __builtin_nontemporal_store(
            v, (f32x4*)(out + (size_t)orow_r * D_ + lane * 4));
    }
}

extern "C" void kernel_launch(void* const* d_in, const int* in_sizes, int n_in,
                              void* d_out, int out_size, void* d_ws, size_t ws_size,
                              hipStream_t stream) {
    const float* tokens  = (const float*)d_in[0];
    const float* W       = (const float*)d_in[1];
    const float* bvec    = (const float*)d_in[2];
    const float* pe      = (const float*)d_in[3];
    const int*   idxs    = (const int*)d_in[4];
    const int*   idxs_pe = (const int*)d_in[5];
    float* out = (float*)d_out;
    __bf16* wpack = (__bf16*)d_ws;   // 128 KB

    pack_w_kernel<<<256, 256, 0, stream>>>(W, wpack);
    embed_kernel<<<S_ * (N_ / 64), 256, 0, stream>>>(tokens, bvec, pe, idxs, idxs_pe,
                                                     wpack, out);
}

// Round 17
// 113.203 us; speedup vs baseline: 1.0257x; 1.0257x over previous
//
#include <hip/hip_runtime.h>
#include <hip/hip_bf16.h>
#include <cstddef>

// Problem constants (EmbeddingEngine_47029891891415)
#define S_ 4
#define N_ 65536
#define K_ 64
#define D_ 256
#define P_ 8192

typedef __bf16 bf16x8 __attribute__((ext_vector_type(8)));
typedef float  f32x4  __attribute__((ext_vector_type(4)));

// Pack W [S][K=64][D=256] fp32 -> bf16 MFMA fragments in ws.
// wpack[(((s*2 + t)*16 + c)*64 + lane)*8 + i] =
//     bf16(W[s][t*32 + 8*(lane>>4) + i][c*16 + (lane&15)])
__global__ __launch_bounds__(256) void pack_w_kernel(const float* __restrict__ W,
                                                     __bf16* __restrict__ wpack) {
    int tid  = blockIdx.x * 256 + threadIdx.x;   // 0..65535
    int i    =  tid        & 7;
    int lane = (tid >> 3)  & 63;
    int c    = (tid >> 9)  & 15;
    int t    = (tid >> 13) & 1;
    int s    =  tid >> 14;
    int k    = t * 32 + 8 * (lane >> 4) + i;
    int col  = c * 16 + (lane & 15);
    wpack[tid] = (__bf16)W[(s * K_ + k) * D_ + col];
}

// R10 (107us champion) + ONE lever: pass-2 pe gathers are ISSUED BEFORE
// pass-1's store burst. Mechanism: vmcnt retirement is in-order; in R10 the
// pass-2 gathers sit behind 16 NT store acks in the VMEM FIFO, so the
// s_waitcnt guarding pass-2's ds_writes drains the full store burst
// (~600-900cy HBM-path ack) every pass boundary. Loads issued AHEAD of the
// stores retire independently -> pass 2 proceeds with stores in flight.
// (Consistent with R12: 4 passes = 3 paid drains = +18us; R16: 0 drains but
// paid residency.) Register cost absorbed: acc[0..7] die as pev2[8] (32
// VGPR) materialize -> peak ~110 < 128, occupancy unchanged (16 waves/CU,
// LDS-capped). Bias folds to post-MFMA (same L2-resident loads, off the
// epilogue critical path). Else byte-identical to R10: NT token loads,
// swapped-operand MFMA (C/D m89/m91: col(lane&15)=token, row(g*4+reg)=d),
// LDS [16][136] transpose, 2-row x 512B contiguous NT bursts.
__global__ __launch_bounds__(256) void embed_kernel(
        const float* __restrict__ tokens,    // [S][N][K] f32
        const float* __restrict__ bvec,      // [S][D] f32
        const float* __restrict__ pe,        // [P][D] f32
        const int*   __restrict__ idxs,      // [S][N] i32
        const int*   __restrict__ idxs_pe,   // [S][N] i32
        const __bf16* __restrict__ wpack,    // packed W fragments (L2)
        float* __restrict__ out) {           // [S*N][D] f32
    const int blk   = blockIdx.x;            // 0..4095
    const int s     = blk >> 10;             // 1024 tiles per stream
    const int tile  = blk & 1023;
    const int wave  = threadIdx.x >> 6;
    const int lane  = threadIdx.x & 63;
    const int j     = lane & 15;             // token within wave tile
    const int g     = lane >> 4;
    const int rowbase = tile * 64 + wave * 16;
    const int trowi   = rowbase + j;         // token row within stream

    __shared__ float lds[4][16][136];        // per-wave [row][128+8 pad]
    float* const wl = &lds[wave][0][0];

    // ---- token fragments: tok[trowi][k], k = t*32 + 8g + e (streaming)
    const float* trow = tokens + ((size_t)s * N_ + trowi) * K_;
    f32x4 t0lo = __builtin_nontemporal_load((const f32x4*)(trow +      8 * g));
    f32x4 t0hi = __builtin_nontemporal_load((const f32x4*)(trow +      8 * g + 4));
    f32x4 t1lo = __builtin_nontemporal_load((const f32x4*)(trow + 32 + 8 * g));
    f32x4 t1hi = __builtin_nontemporal_load((const f32x4*)(trow + 32 + 8 * g + 4));
    bf16x8 a0, a1;
#pragma unroll
    for (int e = 0; e < 4; ++e) {
        a0[e]     = (__bf16)t0lo[e];
        a0[e + 4] = (__bf16)t0hi[e];
        a1[e]     = (__bf16)t1lo[e];
        a1[e + 4] = (__bf16)t1hi[e];
    }

    // ---- W fragments (L2-resident) + MFMA (swapped operands)
    const bf16x8* wp0 = (const bf16x8*)wpack + (size_t)((s * 2 + 0) * 16) * 64;
    const bf16x8* wp1 = (const bf16x8*)wpack + (size_t)((s * 2 + 1) * 16) * 64;

    f32x4 acc[16];
#pragma unroll
    for (int c = 0; c < 16; ++c) acc[c] = (f32x4){0.f, 0.f, 0.f, 0.f};
#pragma unroll
    for (int c = 0; c < 16; ++c) {
        bf16x8 w0 = wp0[c * 64 + lane];
        bf16x8 w1 = wp1[c * 64 + lane];
        acc[c] = __builtin_amdgcn_mfma_f32_16x16x32_bf16(w0, a0, acc[c], 0, 0, 0);
        acc[c] = __builtin_amdgcn_mfma_f32_16x16x32_bf16(w1, a1, acc[c], 0, 0, 0);
    }

    // ---- bias fold (L2-resident loads, off the epilogue critical path)
    const float* __restrict__ brow = bvec + s * D_ + g * 4;
#pragma unroll
    for (int c = 0; c < 16; ++c)
        acc[c] += *(const f32x4*)(brow + c * 16);

    const int ipe  = idxs_pe[s * N_ + trowi];
    const float* __restrict__ perow = pe + (size_t)ipe * D_ + g * 4;
    const int hi = lane >> 5;                // row parity for store phase
    const int lo = lane & 31;                // 32-lane half-row cover

    // ---- pass 1: gather c=0..7, add, stage into LDS
#pragma unroll
    for (int cc = 0; cc < 8; ++cc) {
        f32x4 pev = *(const f32x4*)(perow + cc * 16);
        f32x4 o   = acc[cc] + pev;
        *(f32x4*)(wl + j * 136 + cc * 16 + g * 4) = o;
    }

    // ---- ISSUE pass-2 gathers BEFORE the store burst (vmcnt FIFO: loads
    // ahead of stores retire independently of store acks)
    f32x4 pev2[8];
#pragma unroll
    for (int cc = 0; cc < 8; ++cc)
        pev2[cc] = *(const f32x4*)(perow + (8 + cc) * 16);
    asm volatile("" ::: "memory");   // pin issue order (no sinking past stores)

    // ---- store burst 1: 8 instrs, each 2 rows x 512B contiguous
#pragma unroll
    for (int rr = 0; rr < 8; ++rr) {
        const int r      = rr * 2 + hi;
        const int orow_r = idxs[s * N_ + rowbase + r];
        f32x4 v = *(const f32x4*)(wl + r * 136 + lo * 4);
        __builtin_nontemporal_store(
            v, (f32x4*)(out + (size_t)orow_r * D_ + lo * 4));
    }

    // ---- pass 2: consume prefetched gathers, stage (same LDS region;
    // in-order same-wave DS ops make the WAR on pass-1 reads safe)
#pragma unroll
    for (int cc = 0; cc < 8; ++cc) {
        f32x4 o = acc[8 + cc] + pev2[cc];
        *(f32x4*)(wl + j * 136 + cc * 16 + g * 4) = o;
    }

    // ---- store burst 2
#pragma unroll
    for (int rr = 0; rr < 8; ++rr) {
        const int r      = rr * 2 + hi;
        const int orow_r = idxs[s * N_ + rowbase + r];
        f32x4 v = *(const f32x4*)(wl + r * 136 + lo * 4);
        __builtin_nontemporal_store(
            v, (f32x4*)(out + (size_t)orow_r * D_ + 128 + lo * 4));
    }
}

extern "C" void kernel_launch(void* const* d_in, const int* in_sizes, int n_in,
                              void* d_out, int out_size, void* d_ws, size_t ws_size,
                              hipStream_t stream) {
    const float* tokens  = (const float*)d_in[0];
    const float* W       = (const float*)d_in[1];
    const float* bvec    = (const float*)d_in[2];
    const float* pe      = (const float*)d_in[3];
    const int*   idxs    = (const int*)d_in[4];
    const int*   idxs_pe = (const int*)d_in[5];
    float* out = (float*)d_out;
    __bf16* wpack = (__bf16*)d_ws;   // 128 KB

    pack_w_kernel<<<256, 256, 0, stream>>>(W, wpack);
    embed_kernel<<<S_ * (N_ / 64), 256, 0, stream>>>(tokens, bvec, pe, idxs, idxs_pe,
                                                     wpack, out);
}

// Round 18
// 107.610 us; speedup vs baseline: 1.0790x; 1.0520x over previous
//
#include <hip/hip_runtime.h>
#include <hip/hip_bf16.h>
#include <cstddef>

// Problem constants (EmbeddingEngine_47029891891415)
#define S_ 4
#define N_ 65536
#define K_ 64
#define D_ 256
#define P_ 8192

typedef __bf16 bf16x8 __attribute__((ext_vector_type(8)));
typedef float  f32x4  __attribute__((ext_vector_type(4)));

// Pack W [S][K=64][D=256] fp32 -> bf16 MFMA fragments in ws.
// wpack[(((s*2 + t)*16 + c)*64 + lane)*8 + i] =
//     bf16(W[s][t*32 + 8*(lane>>4) + i][c*16 + (lane&15)])
__global__ __launch_bounds__(256) void pack_w_kernel(const float* __restrict__ W,
                                                     __bf16* __restrict__ wpack) {
    int tid  = blockIdx.x * 256 + threadIdx.x;   // 0..65535
    int i    =  tid        & 7;
    int lane = (tid >> 3)  & 63;
    int c    = (tid >> 9)  & 15;
    int t    = (tid >> 13) & 1;
    int s    =  tid >> 14;
    int k    = t * 32 + 8 * (lane >> 4) + i;
    int col  = c * 16 + (lane & 15);
    wpack[tid] = (__bf16)W[(s * K_ + k) * D_ + col];
}

// CHAMPION (R10, 107.3us): swapped-operand MFMA + LDS-transposed 2-pass
// store epilogue. One block = one stream s, one 64-token tile; 4 waves.
// Lane (j=lane&15, g=lane>>4) owns token rowbase+j, d = c*16 + g*4 + {0..3}
// (C/D layout m89/m91). Each wave stages 8 fragments into a wave-private
// LDS tile [16][136], then emits 8 contiguous NT bursts (2 rows x 512B per
// instr), twice. Landscape mapped (R11-R17): 4-pass=125.7, 2-pass=107.3,
// 1-pass=116.1; store-flag flat; gather bytes/cache null; prefetch/pipeline
// negative (VGPR cliff at 128). This is the measured vertex.
__global__ __launch_bounds__(256) void embed_kernel(
        const float* __restrict__ tokens,    // [S][N][K] f32
        const float* __restrict__ bvec,      // [S][D] f32
        const float* __restrict__ pe,        // [P][D] f32
        const int*   __restrict__ idxs,      // [S][N] i32
        const int*   __restrict__ idxs_pe,   // [S][N] i32
        const __bf16* __restrict__ wpack,    // packed W fragments (L2)
        float* __restrict__ out) {           // [S*N][D] f32
    const int blk   = blockIdx.x;            // 0..4095
    const int s     = blk >> 10;             // 1024 tiles per stream
    const int tile  = blk & 1023;
    const int wave  = threadIdx.x >> 6;
    const int lane  = threadIdx.x & 63;
    const int j     = lane & 15;             // token within wave tile
    const int g     = lane >> 4;
    const int rowbase = tile * 64 + wave * 16;
    const int trowi   = rowbase + j;         // token row within stream

    __shared__ float lds[4][16][136];        // per-wave [row][128+8 pad]
    float* const wl = &lds[wave][0][0];

    // ---- token fragments: tok[trowi][k], k = t*32 + 8g + e (streaming)
    const float* trow = tokens + ((size_t)s * N_ + trowi) * K_;
    f32x4 t0lo = __builtin_nontemporal_load((const f32x4*)(trow +      8 * g));
    f32x4 t0hi = __builtin_nontemporal_load((const f32x4*)(trow +      8 * g + 4));
    f32x4 t1lo = __builtin_nontemporal_load((const f32x4*)(trow + 32 + 8 * g));
    f32x4 t1hi = __builtin_nontemporal_load((const f32x4*)(trow + 32 + 8 * g + 4));
    bf16x8 a0, a1;
#pragma unroll
    for (int e = 0; e < 4; ++e) {
        a0[e]     = (__bf16)t0lo[e];
        a0[e + 4] = (__bf16)t0hi[e];
        a1[e]     = (__bf16)t1lo[e];
        a1[e + 4] = (__bf16)t1hi[e];
    }

    // ---- W fragments (L2-resident) + MFMA (swapped operands)
    const bf16x8* wp0 = (const bf16x8*)wpack + (size_t)((s * 2 + 0) * 16) * 64;
    const bf16x8* wp1 = (const bf16x8*)wpack + (size_t)((s * 2 + 1) * 16) * 64;

    f32x4 acc[16];
#pragma unroll
    for (int c = 0; c < 16; ++c) acc[c] = (f32x4){0.f, 0.f, 0.f, 0.f};
#pragma unroll
    for (int c = 0; c < 16; ++c) {
        bf16x8 w0 = wp0[c * 64 + lane];
        bf16x8 w1 = wp1[c * 64 + lane];
        acc[c] = __builtin_amdgcn_mfma_f32_16x16x32_bf16(w0, a0, acc[c], 0, 0, 0);
        acc[c] = __builtin_amdgcn_mfma_f32_16x16x32_bf16(w1, a1, acc[c], 0, 0, 0);
    }

    // ---- Epilogue
    const int ipe  = idxs_pe[s * N_ + trowi];
    const float* __restrict__ perow = pe + (size_t)ipe * D_ + g * 4;
    const float* __restrict__ brow  = bvec + s * D_ + g * 4;
    const int   hi = lane >> 5;              // row parity for store phase
    const int   lo = lane & 31;              // 32-lane half-row cover

#pragma unroll
    for (int p = 0; p < 2; ++p) {
        // Phase 1: gather pe + add, stage fragment into LDS (wave-private)
#pragma unroll
        for (int cc = 0; cc < 8; ++cc) {
            const int c = p * 8 + cc;
            f32x4 pev = *(const f32x4*)(perow + c * 16);
            f32x4 bbv = *(const f32x4*)(brow  + c * 16);
            f32x4 o   = acc[c] + bbv + pev;
            *(f32x4*)(wl + j * 136 + cc * 16 + g * 4) = o;
        }
        // Phase 2: pure contiguous store burst — 2 rows x 512B per instr
#pragma unroll
        for (int rr = 0; rr < 8; ++rr) {
            const int r      = rr * 2 + hi;
            const int orow_r = idxs[s * N_ + rowbase + r];
            f32x4 v = *(const f32x4*)(wl + r * 136 + lo * 4);
            __builtin_nontemporal_store(
                v, (f32x4*)(out + (size_t)orow_r * D_ + p * 128 + lo * 4));
        }
    }
}

extern "C" void kernel_launch(void* const* d_in, const int* in_sizes, int n_in,
                              void* d_out, int out_size, void* d_ws, size_t ws_size,
                              hipStream_t stream) {
    const float* tokens  = (const float*)d_in[0];
    const float* W       = (const float*)d_in[1];
    const float* bvec    = (const float*)d_in[2];
    const float* pe      = (const float*)d_in[3];
    const int*   idxs    = (const int*)d_in[4];
    const int*   idxs_pe = (const int*)d_in[5];
    float* out = (float*)d_out;
    __bf16* wpack = (__bf16*)d_ws;   // 128 KB

    pack_w_kernel<<<256, 256, 0, stream>>>(W, wpack);
    embed_kernel<<<S_ * (N_ / 64), 256, 0, stream>>>(tokens, bvec, pe, idxs, idxs_pe,
                                                     wpack, out);
}